// Round 6
// baseline (857.543 us; speedup 1.0000x reference)
//
#include <hip/hip_runtime.h>
#include <hip/hip_fp16.h>
#include <cstdint>
#include <cstddef>

// ---------------------------------------------------------------------------
// GATv2 x2 + linear head on MI355X.
// CSR build (hist/scan/scatter -> sorted, src_sorted) + one-time eattr->fp16.
// Per layer: dual GEMM (fp32 math, fp16 table output), edge logits streamed in
// original edge order (fp16 gathers, coalesced fp32 logit write), single-pass
// node softmax+aggregate (fp16 gathers). Final linear fp32. No float atomics.
// ---------------------------------------------------------------------------

__global__ void hist_kernel(const int* __restrict__ dst, int* __restrict__ deg, int E) {
    int e = blockIdx.x * blockDim.x + threadIdx.x;
    if (e < E) atomicAdd(&deg[dst[e]], 1);
}

// single-block exclusive scan, 1024 threads, 4 elems/thread/chunk
__global__ void scan_kernel(const int* __restrict__ deg, int* __restrict__ rowstart, int n) {
    __shared__ int wsum[16];
    int tid = threadIdx.x;
    int lane = tid & 63, wid = tid >> 6;
    int running = 0;
    const int CHUNK = 4096;
    for (int base = 0; base < n; base += CHUNK) {
        int v[4];
        int s = 0;
#pragma unroll
        for (int j = 0; j < 4; ++j) {
            int i = base + tid * 4 + j;
            v[j] = (i < n) ? deg[i] : 0;
            s += v[j];
        }
        int incl = s;
#pragma unroll
        for (int off = 1; off < 64; off <<= 1) {
            int t = __shfl_up(incl, off, 64);
            if (lane >= off) incl += t;
        }
        if (lane == 63) wsum[wid] = incl;
        __syncthreads();
        if (wid == 0) {
            int wv = (lane < 16) ? wsum[lane] : 0;
#pragma unroll
            for (int off = 1; off < 16; off <<= 1) {
                int t = __shfl_up(wv, off, 64);
                if (lane >= off) wv += t;
            }
            if (lane < 16) wsum[lane] = wv;
        }
        __syncthreads();
        int wave_excl = (wid == 0) ? 0 : wsum[wid - 1];
        int acc = running + wave_excl + (incl - s);
#pragma unroll
        for (int j = 0; j < 4; ++j) {
            int i = base + tid * 4 + j;
            if (i < n) rowstart[i] = acc;
            acc += v[j];
        }
        int total = wsum[15];
        __syncthreads();
        running += total;
    }
    if (tid == 0) rowstart[n] = running;
}

// sorted[pos] = edge id; src_sorted[pos] = src[e]
__global__ void scatter_kernel(const int* __restrict__ src, const int* __restrict__ dst,
                               const int* __restrict__ rowstart, int* __restrict__ cursor,
                               int* __restrict__ sorted, int* __restrict__ src_sorted, int E) {
    int e = blockIdx.x * blockDim.x + threadIdx.x;
    if (e < E) {
        int d = dst[e];
        int p = atomicAdd(&cursor[d], 1);
        int pos = rowstart[d] + p;
        sorted[pos] = e;
        src_sorted[pos] = src[e];
    }
}

// fp32 -> fp16 stream convert (8 elems/thread)
__global__ void f2h_kernel(const float* __restrict__ in, __half* __restrict__ out, long n8) {
    long i = (long)blockIdx.x * blockDim.x + threadIdx.x;
    if (i < n8) {
        const float4* s = (const float4*)&in[i * 8];
        float4 a = s[0], b = s[1];
        __half2* d = (__half2*)&out[i * 8];
        d[0] = __float22half2_rn(make_float2(a.x, a.y));
        d[1] = __float22half2_rn(make_float2(a.z, a.w));
        d[2] = __float22half2_rn(make_float2(b.x, b.y));
        d[3] = __float22half2_rn(make_float2(b.z, b.w));
    }
}

__device__ __forceinline__ void fma4(float4& a, float s, const float4& wv) {
    a.x = fmaf(s, wv.x, a.x);
    a.y = fmaf(s, wv.y, a.y);
    a.z = fmaf(s, wv.z, a.z);
    a.w = fmaf(s, wv.w, a.w);
}

// Register-tiled dual GEMM: yl = x@Wl+bl, yr = x@Wr+br (fp16 outputs).
template <int K, int Mh, int BLOCK>
__global__ __launch_bounds__(BLOCK) void gemm_dual(
    const float* __restrict__ x,
    const float* __restrict__ Wl, const float* __restrict__ bl,
    const float* __restrict__ Wr, const float* __restrict__ br,
    __half* __restrict__ yl, __half* __restrict__ yr, int n) {
    constexpr int M = 2 * Mh;
    constexpr int MI = M / 4;        // m-threads
    constexpr int NG = BLOCK / MI;   // node groups
    constexpr int NT = NG * 8;       // nodes per block
    __shared__ float xs[NT * K];
    int tid = threadIdx.x;
    int node0 = blockIdx.x * NT;
    for (int i = tid * 4; i < NT * K; i += BLOCK * 4) {
        int nn = i / K, k = i % K;
        float4 v = make_float4(0.f, 0.f, 0.f, 0.f);
        if (node0 + nn < n) v = *(const float4*)&x[(size_t)(node0 + nn) * K + k];
        *(float4*)&xs[nn * K + k] = v;
    }
    __syncthreads();
    int mi = tid % MI, ng = tid / MI;
    int m0 = mi * 4, nb = ng * 8;
    const float* Wsel;
    const float* bsel;
    __half* ysel;
    int ms;
    if (m0 < Mh) { Wsel = Wl; bsel = bl; ysel = yl; ms = m0; }
    else         { Wsel = Wr; bsel = br; ysel = yr; ms = m0 - Mh; }
    float4 bias = *(const float4*)&bsel[ms];
    float4 acc[8];
#pragma unroll
    for (int nn = 0; nn < 8; ++nn) acc[nn] = bias;
    for (int k0 = 0; k0 < K; k0 += 4) {
        float4 wv0 = *(const float4*)&Wsel[(size_t)(k0 + 0) * Mh + ms];
        float4 wv1 = *(const float4*)&Wsel[(size_t)(k0 + 1) * Mh + ms];
        float4 wv2 = *(const float4*)&Wsel[(size_t)(k0 + 2) * Mh + ms];
        float4 wv3 = *(const float4*)&Wsel[(size_t)(k0 + 3) * Mh + ms];
#pragma unroll
        for (int nn = 0; nn < 8; ++nn) {
            float4 xv = *(const float4*)&xs[(nb + nn) * K + k0];
            fma4(acc[nn], xv.x, wv0);
            fma4(acc[nn], xv.y, wv1);
            fma4(acc[nn], xv.z, wv2);
            fma4(acc[nn], xv.w, wv3);
        }
    }
#pragma unroll
    for (int nn = 0; nn < 8; ++nn) {
        int node = node0 + nb + nn;
        if (node < n) {
            __half2* o = (__half2*)&ysel[(size_t)node * Mh + ms];
            o[0] = __float22half2_rn(make_float2(acc[nn].x, acc[nn].y));
            o[1] = __float22half2_rn(make_float2(acc[nn].z, acc[nn].w));
        }
    }
}

// y[n,M] = x[n,K] @ W[K,M] + b ; fp32 (final head)
template <int K, int M, int NPB>
__global__ void linear_kernel(const float* __restrict__ x, const float* __restrict__ W,
                              const float* __restrict__ b, float* __restrict__ y, int n) {
    __shared__ float sx[NPB * K];
    int tid = threadIdx.x;
    int node0 = blockIdx.x * NPB;
    for (int i = tid; i < NPB * K; i += NPB * M) {
        int nn = node0 + i / K;
        sx[i] = (nn < n) ? x[(size_t)nn * K + (i % K)] : 0.f;
    }
    __syncthreads();
    int ln = tid / M, m = tid % M;
    int node = node0 + ln;
    if (node >= n) return;
    float acc = b[m];
#pragma unroll
    for (int k = 0; k < K; ++k) acc = fmaf(sx[ln * K + k], W[k * M + m], acc);
    y[(size_t)node * M + m] = acc;
}

// Edge logits in ORIGINAL edge order: src/dst/eattr_h streams, fp16 xl/xr
// gathers (128B rows = 1 line). Coalesced fp32 logit write at evals[e*H+h].
template <int H, int C>
__global__ void edge_logits_stream(const int* __restrict__ src, const int* __restrict__ dst,
                                   const __half* __restrict__ eah,  // [E,16] fp16
                                   const float* __restrict__ We,    // [16, HC]
                                   const float* __restrict__ att,   // [HC]
                                   const __half* __restrict__ xl, const __half* __restrict__ xr,
                                   float* __restrict__ evals, int E) {
    constexpr int HC = H * C;
    constexpr int LPE = HC / 2;   // lanes per edge (2 ch each)
    constexpr int EPW = 64 / LPE; // edges per wave
    int lane = threadIdx.x & 63;
    int sub = lane / LPE;
    int j = lane % LPE;
    int ch0 = 2 * j;
    int head = ch0 / C;
    float2 wcol[16];
#pragma unroll
    for (int k = 0; k < 16; ++k) wcol[k] = *(const float2*)&We[k * HC + ch0];
    float2 a2 = *(const float2*)&att[ch0];

    int wave = (blockIdx.x * blockDim.x + threadIdx.x) >> 6;
    int nwaves = (gridDim.x * blockDim.x) >> 6;
    int ngroups = (E + EPW - 1) / EPW;
    for (int g = wave; g < ngroups; g += nwaves) {
        int e = g * EPW + sub;
        bool valid = (e < E);
        int ec = valid ? e : (E - 1);
        int s = src[ec];
        int d = dst[ec];
        // 32B fp16 eattr row (broadcast across the group)
        float4 r0 = *(const float4*)&eah[(size_t)ec * 16];
        float4 r1 = *(const float4*)&eah[(size_t)ec * 16 + 8];
        __half2 xlv2 = *(const __half2*)&xl[(size_t)s * HC + ch0];
        __half2 xrv2 = *(const __half2*)&xr[(size_t)d * HC + ch0];
        float av[16];
        {
            const __half2* h0 = (const __half2*)&r0;
            const __half2* h1 = (const __half2*)&r1;
#pragma unroll
            for (int q = 0; q < 4; ++q) {
                float2 f = __half22float2(h0[q]);
                av[2 * q] = f.x;
                av[2 * q + 1] = f.y;
                float2 g2 = __half22float2(h1[q]);
                av[8 + 2 * q] = g2.x;
                av[8 + 2 * q + 1] = g2.y;
            }
        }
        float2 xlv = __half22float2(xlv2);
        float2 xrv = __half22float2(xrv2);
        float m0 = xlv.x + xrv.x;
        float m1 = xlv.y + xrv.y;
#pragma unroll
        for (int k = 0; k < 16; ++k) {
            m0 = fmaf(av[k], wcol[k].x, m0);
            m1 = fmaf(av[k], wcol[k].y, m1);
        }
        m0 = (m0 > 0.f) ? m0 : 0.2f * m0;
        m1 = (m1 > 0.f) ? m1 : 0.2f * m1;
        float v = m0 * a2.x + m1 * a2.y;
#pragma unroll
        for (int msk = 1; msk < 16; msk <<= 1) v += __shfl_xor(v, msk, 64);
        if (valid && (j & 15) == 0) evals[(size_t)e * H + head] = v;
    }
}

// Single-pass per-node softmax + weighted aggregation (+bias, ELU).
// sorted/src_sorted streams; evals gather (small buf); xl fp16 gather.
template <int H, int C>
__global__ void node_agg_sorted(const int* __restrict__ rowstart,
                                const int* __restrict__ sorted,
                                const int* __restrict__ src_sorted,
                                const float* __restrict__ evals,
                                const __half* __restrict__ xl,
                                const float* __restrict__ bias,
                                float* __restrict__ out, int n) {
    constexpr int HC = H * C;
    constexpr int LPN = HC / 2;
    constexpr int NPW = 64 / LPN;
    int gt = blockIdx.x * blockDim.x + threadIdx.x;
    int wave = gt >> 6;
    int lane = threadIdx.x & 63;
    int sub = lane / LPN;
    int j = lane % LPN;
    int ch0 = 2 * j;
    int head = ch0 / C;
    int node = wave * NPW + sub;
    if (node >= n) return;
    int beg = rowstart[node], end = rowstart[node + 1];
    float denom = 0.f, acc0 = 0.f, acc1 = 0.f;
    for (int p = beg; p < end; ++p) {
        int eid = sorted[p];
        int s = src_sorted[p];
        float w = __expf(evals[(size_t)eid * H + head]);
        float2 xv = __half22float2(*(const __half2*)&xl[(size_t)s * HC + ch0]);
        denom += w;
        acc0 = fmaf(xv.x, w, acc0);
        acc1 = fmaf(xv.y, w, acc1);
    }
    float2 b2 = *(const float2*)&bias[ch0];
    float inv = 1.f / (denom + 1e-16f);
    float o0 = acc0 * inv + b2.x;
    float o1 = acc1 * inv + b2.y;
    o0 = (o0 > 0.f) ? o0 : __expf(o0) - 1.f;
    o1 = (o1 > 0.f) ? o1 : __expf(o1) - 1.f;
    *(float2*)&out[(size_t)node * HC + ch0] = make_float2(o0, o1);
}

extern "C" void kernel_launch(void* const* d_in, const int* in_sizes, int n_in,
                              void* d_out, int out_size, void* d_ws, size_t ws_size,
                              hipStream_t stream) {
    const float* x     = (const float*)d_in[0];
    const int*   eidx  = (const int*)d_in[1];
    const float* eattr = (const float*)d_in[2];
    const float* W1l   = (const float*)d_in[3];
    const float* b1l   = (const float*)d_in[4];
    const float* W1r   = (const float*)d_in[5];
    const float* b1r   = (const float*)d_in[6];
    const float* W1e   = (const float*)d_in[7];
    const float* att1  = (const float*)d_in[8];
    const float* bias1 = (const float*)d_in[9];
    const float* W2l   = (const float*)d_in[10];
    const float* b2l   = (const float*)d_in[11];
    const float* W2r   = (const float*)d_in[12];
    const float* b2r   = (const float*)d_in[13];
    const float* W2e   = (const float*)d_in[14];
    const float* att2  = (const float*)d_in[15];
    const float* bias2 = (const float*)d_in[16];
    const float* Wlin  = (const float*)d_in[17];
    const float* blin  = (const float*)d_in[18];

    const int N = in_sizes[0] / 128;
    const int E = in_sizes[1] / 2;
    const int* src = eidx;
    const int* dst = eidx + E;

    char* p = (char*)d_ws;
    auto take = [&](size_t bytes) {
        char* r = p;
        p += (bytes + 255) & ~(size_t)255;
        return r;
    };
    int*    deg        = (int*)take((size_t)N * sizeof(int));
    int*    cursor     = (int*)take((size_t)N * sizeof(int));
    int*    rowstart   = (int*)take((size_t)(N + 1) * sizeof(int));
    int*    sorted     = (int*)take((size_t)E * sizeof(int));
    int*    src_sorted = (int*)take((size_t)E * sizeof(int));
    __half* A          = (__half*)take((size_t)N * 64 * sizeof(__half));  // xl (fp16)
    __half* B          = (__half*)take((size_t)N * 64 * sizeof(__half));  // xr (fp16)
    float*  Cbuf       = (float*)take((size_t)N * 64 * sizeof(float));    // h1 / h2 (fp32)
    float*  Ebuf       = (float*)take((size_t)E * 2 * sizeof(float));     // logits (edge order)
    __half* eah        = (__half*)take((size_t)E * 16 * sizeof(__half));  // eattr fp16

    // ---- CSR build + eattr convert ----
    (void)hipMemsetAsync(deg, 0, (size_t)N * sizeof(int), stream);
    (void)hipMemsetAsync(cursor, 0, (size_t)N * sizeof(int), stream);
    hist_kernel<<<(E + 255) / 256, 256, 0, stream>>>(dst, deg, E);
    scan_kernel<<<1, 1024, 0, stream>>>(deg, rowstart, N);
    scatter_kernel<<<(E + 255) / 256, 256, 0, stream>>>(src, dst, rowstart, cursor, sorted,
                                                        src_sorted, E);
    {
        long n8 = (long)E * 16 / 8;
        f2h_kernel<<<(int)((n8 + 255) / 256), 256, 0, stream>>>(eattr, eah, n8);
    }

    const int EDGE_GRID = 2048;

    // ---- Layer 1: H=2, C=32 ----
    gemm_dual<128, 64, 256><<<(N + 63) / 64, 256, 0, stream>>>(x, W1l, b1l, W1r, b1r, A, B, N);
    edge_logits_stream<2, 32><<<EDGE_GRID, 256, 0, stream>>>(src, dst, eah, W1e, att1, A, B,
                                                             Ebuf, E);
    node_agg_sorted<2, 32><<<((size_t)(N + 1) / 2 * 64 + 255) / 256, 256, 0, stream>>>(
        rowstart, sorted, src_sorted, Ebuf, A, bias1, Cbuf, N);

    // ---- Layer 2: H=1, C=32 ----
    gemm_dual<64, 32, 256><<<(N + 127) / 128, 256, 0, stream>>>(Cbuf, W2l, b2l, W2r, b2r, A, B, N);
    edge_logits_stream<1, 32><<<EDGE_GRID, 256, 0, stream>>>(src, dst, eah, W2e, att2, A, B,
                                                             Ebuf, E);
    node_agg_sorted<1, 32><<<((size_t)(N + 3) / 4 * 64 + 255) / 256, 256, 0, stream>>>(
        rowstart, sorted, src_sorted, Ebuf, A, bias2, Cbuf, N);

    // ---- Final linear ----
    linear_kernel<32, 32, 8><<<(N + 7) / 8, 256, 0, stream>>>(Cbuf, Wlin, blin, (float*)d_out, N);
}

// Round 7
// 642.786 us; speedup vs baseline: 1.3341x; 1.3341x over previous
//
#include <hip/hip_runtime.h>
#include <hip/hip_fp16.h>
#include <cstdint>
#include <cstddef>

// ---------------------------------------------------------------------------
// GATv2 x2 + linear head on MI355X.
// CSR build (hist/scan/scatter -> sorted, src_sorted) + one-time eattr->fp16.
// Per layer: dual GEMM (fp32 math, fp16 table out) -> FUSED edge-logit +
// softmax + aggregate kernel over dst-sorted edges (xr once/node, xl once/edge,
// no logits buffer). Final linear fp32. No float atomics.
// ---------------------------------------------------------------------------

__global__ void hist_kernel(const int* __restrict__ dst, int* __restrict__ deg, int E) {
    int e = blockIdx.x * blockDim.x + threadIdx.x;
    if (e < E) atomicAdd(&deg[dst[e]], 1);
}

// single-block exclusive scan, 1024 threads, 4 elems/thread/chunk
__global__ void scan_kernel(const int* __restrict__ deg, int* __restrict__ rowstart, int n) {
    __shared__ int wsum[16];
    int tid = threadIdx.x;
    int lane = tid & 63, wid = tid >> 6;
    int running = 0;
    const int CHUNK = 4096;
    for (int base = 0; base < n; base += CHUNK) {
        int v[4];
        int s = 0;
#pragma unroll
        for (int j = 0; j < 4; ++j) {
            int i = base + tid * 4 + j;
            v[j] = (i < n) ? deg[i] : 0;
            s += v[j];
        }
        int incl = s;
#pragma unroll
        for (int off = 1; off < 64; off <<= 1) {
            int t = __shfl_up(incl, off, 64);
            if (lane >= off) incl += t;
        }
        if (lane == 63) wsum[wid] = incl;
        __syncthreads();
        if (wid == 0) {
            int wv = (lane < 16) ? wsum[lane] : 0;
#pragma unroll
            for (int off = 1; off < 16; off <<= 1) {
                int t = __shfl_up(wv, off, 64);
                if (lane >= off) wv += t;
            }
            if (lane < 16) wsum[lane] = wv;
        }
        __syncthreads();
        int wave_excl = (wid == 0) ? 0 : wsum[wid - 1];
        int acc = running + wave_excl + (incl - s);
#pragma unroll
        for (int j = 0; j < 4; ++j) {
            int i = base + tid * 4 + j;
            if (i < n) rowstart[i] = acc;
            acc += v[j];
        }
        int total = wsum[15];
        __syncthreads();
        running += total;
    }
    if (tid == 0) rowstart[n] = running;
}

// sorted[pos] = edge id; src_sorted[pos] = src[e]
__global__ void scatter_kernel(const int* __restrict__ src, const int* __restrict__ dst,
                               const int* __restrict__ rowstart, int* __restrict__ cursor,
                               int* __restrict__ sorted, int* __restrict__ src_sorted, int E) {
    int e = blockIdx.x * blockDim.x + threadIdx.x;
    if (e < E) {
        int d = dst[e];
        int p = atomicAdd(&cursor[d], 1);
        int pos = rowstart[d] + p;
        sorted[pos] = e;
        src_sorted[pos] = src[e];
    }
}

// fp32 -> fp16 stream convert (8 elems/thread)
__global__ void f2h_kernel(const float* __restrict__ in, __half* __restrict__ out, long n8) {
    long i = (long)blockIdx.x * blockDim.x + threadIdx.x;
    if (i < n8) {
        const float4* s = (const float4*)&in[i * 8];
        float4 a = s[0], b = s[1];
        __half2* d = (__half2*)&out[i * 8];
        d[0] = __float22half2_rn(make_float2(a.x, a.y));
        d[1] = __float22half2_rn(make_float2(a.z, a.w));
        d[2] = __float22half2_rn(make_float2(b.x, b.y));
        d[3] = __float22half2_rn(make_float2(b.z, b.w));
    }
}

__device__ __forceinline__ void fma4(float4& a, float s, const float4& wv) {
    a.x = fmaf(s, wv.x, a.x);
    a.y = fmaf(s, wv.y, a.y);
    a.z = fmaf(s, wv.z, a.z);
    a.w = fmaf(s, wv.w, a.w);
}

// Register-tiled dual GEMM: yl = x@Wl+bl, yr = x@Wr+br (fp16 outputs).
template <int K, int Mh, int BLOCK>
__global__ __launch_bounds__(BLOCK) void gemm_dual(
    const float* __restrict__ x,
    const float* __restrict__ Wl, const float* __restrict__ bl,
    const float* __restrict__ Wr, const float* __restrict__ br,
    __half* __restrict__ yl, __half* __restrict__ yr, int n) {
    constexpr int M = 2 * Mh;
    constexpr int MI = M / 4;        // m-threads
    constexpr int NG = BLOCK / MI;   // node groups
    constexpr int NT = NG * 8;       // nodes per block
    __shared__ float xs[NT * K];
    int tid = threadIdx.x;
    int node0 = blockIdx.x * NT;
    for (int i = tid * 4; i < NT * K; i += BLOCK * 4) {
        int nn = i / K, k = i % K;
        float4 v = make_float4(0.f, 0.f, 0.f, 0.f);
        if (node0 + nn < n) v = *(const float4*)&x[(size_t)(node0 + nn) * K + k];
        *(float4*)&xs[nn * K + k] = v;
    }
    __syncthreads();
    int mi = tid % MI, ng = tid / MI;
    int m0 = mi * 4, nb = ng * 8;
    const float* Wsel;
    const float* bsel;
    __half* ysel;
    int ms;
    if (m0 < Mh) { Wsel = Wl; bsel = bl; ysel = yl; ms = m0; }
    else         { Wsel = Wr; bsel = br; ysel = yr; ms = m0 - Mh; }
    float4 bias = *(const float4*)&bsel[ms];
    float4 acc[8];
#pragma unroll
    for (int nn = 0; nn < 8; ++nn) acc[nn] = bias;
    for (int k0 = 0; k0 < K; k0 += 4) {
        float4 wv0 = *(const float4*)&Wsel[(size_t)(k0 + 0) * Mh + ms];
        float4 wv1 = *(const float4*)&Wsel[(size_t)(k0 + 1) * Mh + ms];
        float4 wv2 = *(const float4*)&Wsel[(size_t)(k0 + 2) * Mh + ms];
        float4 wv3 = *(const float4*)&Wsel[(size_t)(k0 + 3) * Mh + ms];
#pragma unroll
        for (int nn = 0; nn < 8; ++nn) {
            float4 xv = *(const float4*)&xs[(nb + nn) * K + k0];
            fma4(acc[nn], xv.x, wv0);
            fma4(acc[nn], xv.y, wv1);
            fma4(acc[nn], xv.z, wv2);
            fma4(acc[nn], xv.w, wv3);
        }
    }
#pragma unroll
    for (int nn = 0; nn < 8; ++nn) {
        int node = node0 + nb + nn;
        if (node < n) {
            __half2* o = (__half2*)&ysel[(size_t)node * Mh + ms];
            o[0] = __float22half2_rn(make_float2(acc[nn].x, acc[nn].y));
            o[1] = __float22half2_rn(make_float2(acc[nn].z, acc[nn].w));
        }
    }
}

// y[n,M] = x[n,K] @ W[K,M] + b ; fp32 (final head)
template <int K, int M, int NPB>
__global__ void linear_kernel(const float* __restrict__ x, const float* __restrict__ W,
                              const float* __restrict__ b, float* __restrict__ y, int n) {
    __shared__ float sx[NPB * K];
    int tid = threadIdx.x;
    int node0 = blockIdx.x * NPB;
    for (int i = tid; i < NPB * K; i += NPB * M) {
        int nn = node0 + i / K;
        sx[i] = (nn < n) ? x[(size_t)nn * K + (i % K)] : 0.f;
    }
    __syncthreads();
    int ln = tid / M, m = tid % M;
    int node = node0 + ln;
    if (node >= n) return;
    float acc = b[m];
#pragma unroll
    for (int k = 0; k < K; ++k) acc = fmaf(sx[ln * K + k], W[k * M + m], acc);
    y[(size_t)node * M + m] = acc;
}

// FUSED edge-logit + softmax + aggregate over dst-sorted edges.
// LPN = HC/2 lanes per node (2 ch/lane); xr loaded once per node; per edge:
// eattr fp16 32B broadcast + xl fp16 row gather, reused for logit AND accum.
template <int H, int C>
__global__ __launch_bounds__(256) void fused_edge_agg(
    const int* __restrict__ rowstart, const int* __restrict__ sorted,
    const int* __restrict__ src_sorted, const __half* __restrict__ eah,
    const float* __restrict__ We,    // [16, HC]
    const float* __restrict__ att,   // [HC]
    const __half* __restrict__ xl, const __half* __restrict__ xr,
    const float* __restrict__ bias, float* __restrict__ out, int n) {
    constexpr int HC = H * C;
    constexpr int LPN = HC / 2;   // lanes per node
    constexpr int NPW = 64 / LPN; // nodes per wave
    int gt = blockIdx.x * blockDim.x + threadIdx.x;
    int wave = gt >> 6;
    int lane = threadIdx.x & 63;
    int sub = lane / LPN;
    int j = lane % LPN;
    int ch0 = 2 * j;
    int node = wave * NPW + sub;
    if (node >= n) return;
    float2 wcol[16];
#pragma unroll
    for (int k = 0; k < 16; ++k) wcol[k] = *(const float2*)&We[k * HC + ch0];
    float2 a2 = *(const float2*)&att[ch0];
    float2 xr2 = __half22float2(*(const __half2*)&xr[(size_t)node * HC + ch0]);
    int beg = rowstart[node], end = rowstart[node + 1];
    float denom = 0.f, acc0 = 0.f, acc1 = 0.f;

    auto edge_mv = [&](int pp, float& m0, float& m1, float2& xl2) {
        int eid = sorted[pp];
        int s = src_sorted[pp];
        float4 r0 = *(const float4*)&eah[(size_t)eid * 16];
        float4 r1 = *(const float4*)&eah[(size_t)eid * 16 + 8];
        xl2 = __half22float2(*(const __half2*)&xl[(size_t)s * HC + ch0]);
        float av[16];
        const __half2* h0 = (const __half2*)&r0;
        const __half2* h1 = (const __half2*)&r1;
#pragma unroll
        for (int q = 0; q < 4; ++q) {
            float2 f = __half22float2(h0[q]);
            av[2 * q] = f.x;
            av[2 * q + 1] = f.y;
            float2 g2 = __half22float2(h1[q]);
            av[8 + 2 * q] = g2.x;
            av[8 + 2 * q + 1] = g2.y;
        }
        m0 = xl2.x + xr2.x;
        m1 = xl2.y + xr2.y;
#pragma unroll
        for (int k = 0; k < 16; ++k) {
            m0 = fmaf(av[k], wcol[k].x, m0);
            m1 = fmaf(av[k], wcol[k].y, m1);
        }
    };
    auto logit = [&](float m0, float m1) -> float {
        m0 = (m0 > 0.f) ? m0 : 0.2f * m0;
        m1 = (m1 > 0.f) ? m1 : 0.2f * m1;
        float v = m0 * a2.x + m1 * a2.y;
        // sum over the 16 lanes covering this head (C/2 = 16 both layers)
#pragma unroll
        for (int msk = 1; msk < 16; msk <<= 1) v += __shfl_xor(v, msk, 64);
        return v;
    };

    int pp = beg;
    for (; pp + 2 <= end; pp += 2) {
        float m0a, m1a, m0b, m1b;
        float2 xla, xlb;
        edge_mv(pp, m0a, m1a, xla);
        edge_mv(pp + 1, m0b, m1b, xlb);
        float va = logit(m0a, m1a);
        float vb = logit(m0b, m1b);
        float wa = __expf(va), wb = __expf(vb);
        denom += wa + wb;
        acc0 = fmaf(xla.x, wa, acc0);
        acc1 = fmaf(xla.y, wa, acc1);
        acc0 = fmaf(xlb.x, wb, acc0);
        acc1 = fmaf(xlb.y, wb, acc1);
    }
    if (pp < end) {
        float m0a, m1a;
        float2 xla;
        edge_mv(pp, m0a, m1a, xla);
        float va = logit(m0a, m1a);
        float wa = __expf(va);
        denom += wa;
        acc0 = fmaf(xla.x, wa, acc0);
        acc1 = fmaf(xla.y, wa, acc1);
    }
    float2 b2 = *(const float2*)&bias[ch0];
    float inv = 1.f / (denom + 1e-16f);
    float o0 = acc0 * inv + b2.x;
    float o1 = acc1 * inv + b2.y;
    o0 = (o0 > 0.f) ? o0 : __expf(o0) - 1.f;
    o1 = (o1 > 0.f) ? o1 : __expf(o1) - 1.f;
    *(float2*)&out[(size_t)node * HC + ch0] = make_float2(o0, o1);
}

extern "C" void kernel_launch(void* const* d_in, const int* in_sizes, int n_in,
                              void* d_out, int out_size, void* d_ws, size_t ws_size,
                              hipStream_t stream) {
    const float* x     = (const float*)d_in[0];
    const int*   eidx  = (const int*)d_in[1];
    const float* eattr = (const float*)d_in[2];
    const float* W1l   = (const float*)d_in[3];
    const float* b1l   = (const float*)d_in[4];
    const float* W1r   = (const float*)d_in[5];
    const float* b1r   = (const float*)d_in[6];
    const float* W1e   = (const float*)d_in[7];
    const float* att1  = (const float*)d_in[8];
    const float* bias1 = (const float*)d_in[9];
    const float* W2l   = (const float*)d_in[10];
    const float* b2l   = (const float*)d_in[11];
    const float* W2r   = (const float*)d_in[12];
    const float* b2r   = (const float*)d_in[13];
    const float* W2e   = (const float*)d_in[14];
    const float* att2  = (const float*)d_in[15];
    const float* bias2 = (const float*)d_in[16];
    const float* Wlin  = (const float*)d_in[17];
    const float* blin  = (const float*)d_in[18];

    const int N = in_sizes[0] / 128;
    const int E = in_sizes[1] / 2;
    const int* src = eidx;
    const int* dst = eidx + E;

    char* p = (char*)d_ws;
    auto take = [&](size_t bytes) {
        char* r = p;
        p += (bytes + 255) & ~(size_t)255;
        return r;
    };
    int*    deg        = (int*)take((size_t)N * sizeof(int));
    int*    cursor     = (int*)take((size_t)N * sizeof(int));
    int*    rowstart   = (int*)take((size_t)(N + 1) * sizeof(int));
    int*    sorted     = (int*)take((size_t)E * sizeof(int));
    int*    src_sorted = (int*)take((size_t)E * sizeof(int));
    __half* A          = (__half*)take((size_t)N * 64 * sizeof(__half));  // xl (fp16)
    __half* B          = (__half*)take((size_t)N * 64 * sizeof(__half));  // xr (fp16)
    float*  Cbuf       = (float*)take((size_t)N * 64 * sizeof(float));    // h1 / h2 (fp32)
    __half* eah        = (__half*)take((size_t)E * 16 * sizeof(__half));  // eattr fp16

    // ---- CSR build + eattr convert ----
    (void)hipMemsetAsync(deg, 0, (size_t)N * sizeof(int), stream);
    (void)hipMemsetAsync(cursor, 0, (size_t)N * sizeof(int), stream);
    hist_kernel<<<(E + 255) / 256, 256, 0, stream>>>(dst, deg, E);
    scan_kernel<<<1, 1024, 0, stream>>>(deg, rowstart, N);
    scatter_kernel<<<(E + 255) / 256, 256, 0, stream>>>(src, dst, rowstart, cursor, sorted,
                                                        src_sorted, E);
    {
        long n8 = (long)E * 16 / 8;
        f2h_kernel<<<(int)((n8 + 255) / 256), 256, 0, stream>>>(eattr, eah, n8);
    }

    // ---- Layer 1: H=2, C=32 (2 nodes/wave) ----
    gemm_dual<128, 64, 256><<<(N + 63) / 64, 256, 0, stream>>>(x, W1l, b1l, W1r, b1r, A, B, N);
    fused_edge_agg<2, 32><<<(int)(((size_t)((N + 1) / 2) * 64 + 255) / 256), 256, 0, stream>>>(
        rowstart, sorted, src_sorted, eah, W1e, att1, A, B, bias1, Cbuf, N);

    // ---- Layer 2: H=1, C=32 (4 nodes/wave) ----
    gemm_dual<64, 32, 256><<<(N + 127) / 128, 256, 0, stream>>>(Cbuf, W2l, b2l, W2r, b2r, A, B, N);
    fused_edge_agg<1, 32><<<(int)(((size_t)((N + 3) / 4) * 64 + 255) / 256), 256, 0, stream>>>(
        rowstart, sorted, src_sorted, eah, W2e, att2, A, B, bias2, Cbuf, N);

    // ---- Final linear ----
    linear_kernel<32, 32, 8><<<(N + 7) / 8, 256, 0, stream>>>(Cbuf, Wlin, blin, (float*)d_out, N);
}

// Round 8
// 468.438 us; speedup vs baseline: 1.8306x; 1.3722x over previous
//
#include <hip/hip_runtime.h>
#include <hip/hip_fp16.h>
#include <cstdint>
#include <cstddef>

// ---------------------------------------------------------------------------
// GATv2 x2 + linear head on MI355X.
// CSR build (hist / 3-phase multi-block scan / scatter -> es=(eid,src) int2)
// + one-time eattr->fp16. Per layer: dual GEMM (fp32 math, fp16 table out) ->
// FUSED edge-logit+softmax+aggregate over dst-sorted edges with packed-fp16
// ea@We GEMV. Final linear fp32. No float atomics.
// ---------------------------------------------------------------------------

__global__ void hist_kernel(const int* __restrict__ dst, int* __restrict__ deg, int E) {
    int e = blockIdx.x * blockDim.x + threadIdx.x;
    if (e < E) atomicAdd(&deg[dst[e]], 1);
}

// ---- 3-phase exclusive scan of deg[0..n) -> rowstart[0..n] ----
// phase 1: per-block (1024 elems) sums
__global__ void scan_part(const int* __restrict__ deg, int* __restrict__ bsum, int n) {
    int tid = threadIdx.x;
    int base = blockIdx.x * 1024 + tid * 4;
    int s = 0;
#pragma unroll
    for (int j = 0; j < 4; ++j) {
        int i = base + j;
        if (i < n) s += deg[i];
    }
#pragma unroll
    for (int off = 1; off < 64; off <<= 1) s += __shfl_xor(s, off, 64);
    __shared__ int ws[4];
    if ((tid & 63) == 0) ws[tid >> 6] = s;
    __syncthreads();
    if (tid == 0) bsum[blockIdx.x] = ws[0] + ws[1] + ws[2] + ws[3];
}

// phase 2: single block (128 threads) exclusive-scans bsum[nb] (nb<=128),
// writes rowstart[n] = total
__global__ void scan_mid(int* __restrict__ bsum, int* __restrict__ rowstart, int nb, int n) {
    int tid = threadIdx.x;
    int v = (tid < nb) ? bsum[tid] : 0;
    int incl = v;
#pragma unroll
    for (int off = 1; off < 64; off <<= 1) {
        int t = __shfl_up(incl, off, 64);
        if ((tid & 63) >= off) incl += t;
    }
    __shared__ int w0;
    if (tid == 63) w0 = incl;
    __syncthreads();
    if (tid >= 64) incl += w0;
    if (tid < nb) bsum[tid] = incl - v;
    if (tid == nb - 1) rowstart[n] = incl;
}

// phase 3: per-block local exclusive scan + block offset
__global__ void scan_fin(const int* __restrict__ deg, const int* __restrict__ bsum,
                         int* __restrict__ rowstart, int n) {
    int tid = threadIdx.x;
    int lane = tid & 63, wid = tid >> 6;
    int base = blockIdx.x * 1024 + tid * 4;
    int v[4];
    int s = 0;
#pragma unroll
    for (int j = 0; j < 4; ++j) {
        int i = base + j;
        v[j] = (i < n) ? deg[i] : 0;
        s += v[j];
    }
    int incl = s;
#pragma unroll
    for (int off = 1; off < 64; off <<= 1) {
        int t = __shfl_up(incl, off, 64);
        if (lane >= off) incl += t;
    }
    __shared__ int ws[4];
    if (lane == 63) ws[wid] = incl;
    __syncthreads();
    int wofs = 0;
    for (int w2 = 0; w2 < wid; ++w2) wofs += ws[w2];
    int acc = bsum[blockIdx.x] + wofs + (incl - s);
#pragma unroll
    for (int j = 0; j < 4; ++j) {
        int i = base + j;
        if (i < n) rowstart[i] = acc;
        acc += v[j];
    }
}

// es[pos] = (edge id, src)
__global__ void scatter_kernel(const int* __restrict__ src, const int* __restrict__ dst,
                               const int* __restrict__ rowstart, int* __restrict__ cursor,
                               int2* __restrict__ es, int E) {
    int e = blockIdx.x * blockDim.x + threadIdx.x;
    if (e < E) {
        int d = dst[e];
        int p = atomicAdd(&cursor[d], 1);
        es[rowstart[d] + p] = make_int2(e, src[e]);
    }
}

// fp32 -> fp16 stream convert (8 elems/thread)
__global__ void f2h_kernel(const float* __restrict__ in, __half* __restrict__ out, long n8) {
    long i = (long)blockIdx.x * blockDim.x + threadIdx.x;
    if (i < n8) {
        const float4* s = (const float4*)&in[i * 8];
        float4 a = s[0], b = s[1];
        __half2* d = (__half2*)&out[i * 8];
        d[0] = __float22half2_rn(make_float2(a.x, a.y));
        d[1] = __float22half2_rn(make_float2(a.z, a.w));
        d[2] = __float22half2_rn(make_float2(b.x, b.y));
        d[3] = __float22half2_rn(make_float2(b.z, b.w));
    }
}

__device__ __forceinline__ void fma4(float4& a, float s, const float4& wv) {
    a.x = fmaf(s, wv.x, a.x);
    a.y = fmaf(s, wv.y, a.y);
    a.z = fmaf(s, wv.z, a.z);
    a.w = fmaf(s, wv.w, a.w);
}

// Register-tiled dual GEMM: yl = x@Wl+bl, yr = x@Wr+br (fp16 outputs).
template <int K, int Mh, int BLOCK>
__global__ __launch_bounds__(BLOCK) void gemm_dual(
    const float* __restrict__ x,
    const float* __restrict__ Wl, const float* __restrict__ bl,
    const float* __restrict__ Wr, const float* __restrict__ br,
    __half* __restrict__ yl, __half* __restrict__ yr, int n) {
    constexpr int M = 2 * Mh;
    constexpr int MI = M / 4;
    constexpr int NG = BLOCK / MI;
    constexpr int NT = NG * 8;
    __shared__ float xs[NT * K];
    int tid = threadIdx.x;
    int node0 = blockIdx.x * NT;
    for (int i = tid * 4; i < NT * K; i += BLOCK * 4) {
        int nn = i / K, k = i % K;
        float4 v = make_float4(0.f, 0.f, 0.f, 0.f);
        if (node0 + nn < n) v = *(const float4*)&x[(size_t)(node0 + nn) * K + k];
        *(float4*)&xs[nn * K + k] = v;
    }
    __syncthreads();
    int mi = tid % MI, ng = tid / MI;
    int m0 = mi * 4, nb = ng * 8;
    const float* Wsel;
    const float* bsel;
    __half* ysel;
    int ms;
    if (m0 < Mh) { Wsel = Wl; bsel = bl; ysel = yl; ms = m0; }
    else         { Wsel = Wr; bsel = br; ysel = yr; ms = m0 - Mh; }
    float4 bias = *(const float4*)&bsel[ms];
    float4 acc[8];
#pragma unroll
    for (int nn = 0; nn < 8; ++nn) acc[nn] = bias;
    for (int k0 = 0; k0 < K; k0 += 4) {
        float4 wv0 = *(const float4*)&Wsel[(size_t)(k0 + 0) * Mh + ms];
        float4 wv1 = *(const float4*)&Wsel[(size_t)(k0 + 1) * Mh + ms];
        float4 wv2 = *(const float4*)&Wsel[(size_t)(k0 + 2) * Mh + ms];
        float4 wv3 = *(const float4*)&Wsel[(size_t)(k0 + 3) * Mh + ms];
#pragma unroll
        for (int nn = 0; nn < 8; ++nn) {
            float4 xv = *(const float4*)&xs[(nb + nn) * K + k0];
            fma4(acc[nn], xv.x, wv0);
            fma4(acc[nn], xv.y, wv1);
            fma4(acc[nn], xv.z, wv2);
            fma4(acc[nn], xv.w, wv3);
        }
    }
#pragma unroll
    for (int nn = 0; nn < 8; ++nn) {
        int node = node0 + nb + nn;
        if (node < n) {
            __half2* o = (__half2*)&ysel[(size_t)node * Mh + ms];
            o[0] = __float22half2_rn(make_float2(acc[nn].x, acc[nn].y));
            o[1] = __float22half2_rn(make_float2(acc[nn].z, acc[nn].w));
        }
    }
}

// y[n,M] = x[n,K] @ W[K,M] + b ; fp32 (final head)
template <int K, int M, int NPB>
__global__ void linear_kernel(const float* __restrict__ x, const float* __restrict__ W,
                              const float* __restrict__ b, float* __restrict__ y, int n) {
    __shared__ float sx[NPB * K];
    int tid = threadIdx.x;
    int node0 = blockIdx.x * NPB;
    for (int i = tid; i < NPB * K; i += NPB * M) {
        int nn = node0 + i / K;
        sx[i] = (nn < n) ? x[(size_t)nn * K + (i % K)] : 0.f;
    }
    __syncthreads();
    int ln = tid / M, m = tid % M;
    int node = node0 + ln;
    if (node >= n) return;
    float acc = b[m];
#pragma unroll
    for (int k = 0; k < K; ++k) acc = fmaf(sx[ln * K + k], W[k * M + m], acc);
    y[(size_t)node * M + m] = acc;
}

// FUSED edge-logit + softmax + aggregate over dst-sorted edges.
// 2 ch/lane; xr once per node; per edge: int2 record + fp16 eattr 32B
// broadcast + fp16 xl row gather; ea@We via packed v_pk_fma_f16.
template <int H, int C>
__global__ __launch_bounds__(256) void fused_edge_agg(
    const int* __restrict__ rowstart, const int2* __restrict__ es,
    const __half* __restrict__ eah,
    const float* __restrict__ We,    // [16, HC]
    const float* __restrict__ att,   // [HC]
    const __half* __restrict__ xl, const __half* __restrict__ xr,
    const float* __restrict__ bias, float* __restrict__ out, int n) {
    constexpr int HC = H * C;
    constexpr int LPN = HC / 2;   // lanes per node
    constexpr int NPW = 64 / LPN; // nodes per wave
    int gt = blockIdx.x * blockDim.x + threadIdx.x;
    int wave = gt >> 6;
    int lane = threadIdx.x & 63;
    int sub = lane / LPN;
    int j = lane % LPN;
    int ch0 = 2 * j;
    int node = wave * NPW + sub;
    if (node >= n) return;
    __half2 wh[16];
#pragma unroll
    for (int k = 0; k < 16; ++k) wh[k] = __float22half2_rn(*(const float2*)&We[k * HC + ch0]);
    float2 a2 = *(const float2*)&att[ch0];
    float2 xr2 = __half22float2(*(const __half2*)&xr[(size_t)node * HC + ch0]);
    int beg = rowstart[node], end = rowstart[node + 1];
    float denom = 0.f, acc0 = 0.f, acc1 = 0.f;

    auto edge_mv = [&](int pp, float& m0, float& m1, float2& xlf) {
        int2 e2 = es[pp];
        const float4* ea4 = (const float4*)&eah[(size_t)e2.x * 16];
        float4 r0 = ea4[0], r1 = ea4[1];
        __half2 xlh = *(const __half2*)&xl[(size_t)e2.y * HC + ch0];
        const __half2* h0 = (const __half2*)&r0;
        const __half2* h1 = (const __half2*)&r1;
        // two 8-deep packed chains (op_sel splats fold into v_pk_fma_f16)
        __half2 p0 = __hmul2(__low2half2(h0[0]), wh[0]);
        __half2 p1 = __hmul2(__high2half2(h0[0]), wh[1]);
        p0 = __hfma2(__low2half2(h0[1]), wh[2], p0);
        p1 = __hfma2(__high2half2(h0[1]), wh[3], p1);
        p0 = __hfma2(__low2half2(h0[2]), wh[4], p0);
        p1 = __hfma2(__high2half2(h0[2]), wh[5], p1);
        p0 = __hfma2(__low2half2(h0[3]), wh[6], p0);
        p1 = __hfma2(__high2half2(h0[3]), wh[7], p1);
        p0 = __hfma2(__low2half2(h1[0]), wh[8], p0);
        p1 = __hfma2(__high2half2(h1[0]), wh[9], p1);
        p0 = __hfma2(__low2half2(h1[1]), wh[10], p0);
        p1 = __hfma2(__high2half2(h1[1]), wh[11], p1);
        p0 = __hfma2(__low2half2(h1[2]), wh[12], p0);
        p1 = __hfma2(__high2half2(h1[2]), wh[13], p1);
        p0 = __hfma2(__low2half2(h1[3]), wh[14], p0);
        p1 = __hfma2(__high2half2(h1[3]), wh[15], p1);
        float2 mf = __half22float2(__hadd2(p0, p1));
        xlf = __half22float2(xlh);
        m0 = xlf.x + xr2.x + mf.x;
        m1 = xlf.y + xr2.y + mf.y;
    };
    auto logit = [&](float m0, float m1) -> float {
        m0 = (m0 > 0.f) ? m0 : 0.2f * m0;
        m1 = (m1 > 0.f) ? m1 : 0.2f * m1;
        float v = m0 * a2.x + m1 * a2.y;
#pragma unroll
        for (int msk = 1; msk < 16; msk <<= 1) v += __shfl_xor(v, msk, 64);
        return v;
    };

    int pp = beg;
    for (; pp + 2 <= end; pp += 2) {
        float m0a, m1a, m0b, m1b;
        float2 xla, xlb;
        edge_mv(pp, m0a, m1a, xla);
        edge_mv(pp + 1, m0b, m1b, xlb);
        float wa = __expf(logit(m0a, m1a));
        float wb = __expf(logit(m0b, m1b));
        denom += wa + wb;
        acc0 = fmaf(xla.x, wa, acc0);
        acc1 = fmaf(xla.y, wa, acc1);
        acc0 = fmaf(xlb.x, wb, acc0);
        acc1 = fmaf(xlb.y, wb, acc1);
    }
    if (pp < end) {
        float m0a, m1a;
        float2 xla;
        edge_mv(pp, m0a, m1a, xla);
        float wa = __expf(logit(m0a, m1a));
        denom += wa;
        acc0 = fmaf(xla.x, wa, acc0);
        acc1 = fmaf(xla.y, wa, acc1);
    }
    float2 b2 = *(const float2*)&bias[ch0];
    float inv = 1.f / (denom + 1e-16f);
    float o0 = acc0 * inv + b2.x;
    float o1 = acc1 * inv + b2.y;
    o0 = (o0 > 0.f) ? o0 : __expf(o0) - 1.f;
    o1 = (o1 > 0.f) ? o1 : __expf(o1) - 1.f;
    *(float2*)&out[(size_t)node * HC + ch0] = make_float2(o0, o1);
}

extern "C" void kernel_launch(void* const* d_in, const int* in_sizes, int n_in,
                              void* d_out, int out_size, void* d_ws, size_t ws_size,
                              hipStream_t stream) {
    const float* x     = (const float*)d_in[0];
    const int*   eidx  = (const int*)d_in[1];
    const float* eattr = (const float*)d_in[2];
    const float* W1l   = (const float*)d_in[3];
    const float* b1l   = (const float*)d_in[4];
    const float* W1r   = (const float*)d_in[5];
    const float* b1r   = (const float*)d_in[6];
    const float* W1e   = (const float*)d_in[7];
    const float* att1  = (const float*)d_in[8];
    const float* bias1 = (const float*)d_in[9];
    const float* W2l   = (const float*)d_in[10];
    const float* b2l   = (const float*)d_in[11];
    const float* W2r   = (const float*)d_in[12];
    const float* b2r   = (const float*)d_in[13];
    const float* W2e   = (const float*)d_in[14];
    const float* att2  = (const float*)d_in[15];
    const float* bias2 = (const float*)d_in[16];
    const float* Wlin  = (const float*)d_in[17];
    const float* blin  = (const float*)d_in[18];

    const int N = in_sizes[0] / 128;
    const int E = in_sizes[1] / 2;
    const int* src = eidx;
    const int* dst = eidx + E;

    char* p = (char*)d_ws;
    auto take = [&](size_t bytes) {
        char* r = p;
        p += (bytes + 255) & ~(size_t)255;
        return r;
    };
    int*    deg      = (int*)take((size_t)N * sizeof(int));
    int*    cursor   = (int*)take((size_t)N * sizeof(int));
    int*    rowstart = (int*)take((size_t)(N + 1) * sizeof(int));
    int*    bsum     = (int*)take(256 * sizeof(int));
    int2*   es       = (int2*)take((size_t)E * sizeof(int2));
    __half* A        = (__half*)take((size_t)N * 64 * sizeof(__half));  // xl (fp16)
    __half* B        = (__half*)take((size_t)N * 64 * sizeof(__half));  // xr (fp16)
    float*  Cbuf     = (float*)take((size_t)N * 64 * sizeof(float));    // h1 / h2 (fp32)
    __half* eah      = (__half*)take((size_t)E * 16 * sizeof(__half));  // eattr fp16

    // ---- CSR build + eattr convert ----
    (void)hipMemsetAsync(deg, 0, (size_t)N * sizeof(int), stream);
    (void)hipMemsetAsync(cursor, 0, (size_t)N * sizeof(int), stream);
    hist_kernel<<<(E + 255) / 256, 256, 0, stream>>>(dst, deg, E);
    {
        int nb = (N + 1023) / 1024;  // 98 for N=100000 (<=128)
        scan_part<<<nb, 256, 0, stream>>>(deg, bsum, N);
        scan_mid<<<1, 128, 0, stream>>>(bsum, rowstart, nb, N);
        scan_fin<<<nb, 256, 0, stream>>>(deg, bsum, rowstart, N);
    }
    scatter_kernel<<<(E + 255) / 256, 256, 0, stream>>>(src, dst, rowstart, cursor, es, E);
    {
        long n8 = (long)E * 16 / 8;
        f2h_kernel<<<(int)((n8 + 255) / 256), 256, 0, stream>>>(eattr, eah, n8);
    }

    // ---- Layer 1: H=2, C=32 (2 nodes/wave) ----
    gemm_dual<128, 64, 256><<<(N + 63) / 64, 256, 0, stream>>>(x, W1l, b1l, W1r, b1r, A, B, N);
    fused_edge_agg<2, 32><<<(int)(((size_t)((N + 1) / 2) * 64 + 255) / 256), 256, 0, stream>>>(
        rowstart, es, eah, W1e, att1, A, B, bias1, Cbuf, N);

    // ---- Layer 2: H=1, C=32 (4 nodes/wave) ----
    gemm_dual<64, 32, 256><<<(N + 127) / 128, 256, 0, stream>>>(Cbuf, W2l, b2l, W2r, b2r, A, B, N);
    fused_edge_agg<1, 32><<<(int)(((size_t)((N + 3) / 4) * 64 + 255) / 256), 256, 0, stream>>>(
        rowstart, es, eah, W2e, att2, A, B, bias2, Cbuf, N);

    // ---- Final linear ----
    linear_kernel<32, 32, 8><<<(N + 7) / 8, 256, 0, stream>>>(Cbuf, Wlin, blin, (float*)d_out, N);
}

// Round 9
// 444.084 us; speedup vs baseline: 1.9310x; 1.0548x over previous
//
#include <hip/hip_runtime.h>
#include <hip/hip_fp16.h>
#include <cstdint>
#include <cstddef>

// ---------------------------------------------------------------------------
// GATv2 x2 + linear head on MI355X.
// CSR build (hist / 3-phase scan / scatter -> es=(eid,src)) + eattr->fp16 +
// weight repack to MFMA fragment order. Per layer: MFMA dual GEMM (fp16 in,
// fp32 accum, fp16 table out) -> FUSED edge-logit+softmax+aggregate (packed
// fp16 GEMV, 4-edge unrolled gathers). Final linear fp32. No float atomics.
// ---------------------------------------------------------------------------

typedef _Float16 half8 __attribute__((ext_vector_type(8)));
typedef float f32x4 __attribute__((ext_vector_type(4)));

__global__ void hist_kernel(const int* __restrict__ dst, int* __restrict__ deg, int E) {
    int e = blockIdx.x * blockDim.x + threadIdx.x;
    if (e < E) atomicAdd(&deg[dst[e]], 1);
}

// ---- 3-phase exclusive scan of deg[0..n) -> rowstart[0..n] ----
__global__ void scan_part(const int* __restrict__ deg, int* __restrict__ bsum, int n) {
    int tid = threadIdx.x;
    int base = blockIdx.x * 1024 + tid * 4;
    int s = 0;
#pragma unroll
    for (int j = 0; j < 4; ++j) {
        int i = base + j;
        if (i < n) s += deg[i];
    }
#pragma unroll
    for (int off = 1; off < 64; off <<= 1) s += __shfl_xor(s, off, 64);
    __shared__ int ws[4];
    if ((tid & 63) == 0) ws[tid >> 6] = s;
    __syncthreads();
    if (tid == 0) bsum[blockIdx.x] = ws[0] + ws[1] + ws[2] + ws[3];
}

__global__ void scan_mid(int* __restrict__ bsum, int* __restrict__ rowstart, int nb, int n) {
    int tid = threadIdx.x;
    int v = (tid < nb) ? bsum[tid] : 0;
    int incl = v;
#pragma unroll
    for (int off = 1; off < 64; off <<= 1) {
        int t = __shfl_up(incl, off, 64);
        if ((tid & 63) >= off) incl += t;
    }
    __shared__ int w0;
    if (tid == 63) w0 = incl;
    __syncthreads();
    if (tid >= 64) incl += w0;
    if (tid < nb) bsum[tid] = incl - v;
    if (tid == nb - 1) rowstart[n] = incl;
}

__global__ void scan_fin(const int* __restrict__ deg, const int* __restrict__ bsum,
                         int* __restrict__ rowstart, int n) {
    int tid = threadIdx.x;
    int lane = tid & 63, wid = tid >> 6;
    int base = blockIdx.x * 1024 + tid * 4;
    int v[4];
    int s = 0;
#pragma unroll
    for (int j = 0; j < 4; ++j) {
        int i = base + j;
        v[j] = (i < n) ? deg[i] : 0;
        s += v[j];
    }
    int incl = s;
#pragma unroll
    for (int off = 1; off < 64; off <<= 1) {
        int t = __shfl_up(incl, off, 64);
        if (lane >= off) incl += t;
    }
    __shared__ int ws[4];
    if (lane == 63) ws[wid] = incl;
    __syncthreads();
    int wofs = 0;
    for (int w2 = 0; w2 < wid; ++w2) wofs += ws[w2];
    int acc = bsum[blockIdx.x] + wofs + (incl - s);
#pragma unroll
    for (int j = 0; j < 4; ++j) {
        int i = base + j;
        if (i < n) rowstart[i] = acc;
        acc += v[j];
    }
}

// es[pos] = (edge id, src)
__global__ void scatter_kernel(const int* __restrict__ src, const int* __restrict__ dst,
                               const int* __restrict__ rowstart, int* __restrict__ cursor,
                               int2* __restrict__ es, int E) {
    int e = blockIdx.x * blockDim.x + threadIdx.x;
    if (e < E) {
        int d = dst[e];
        int p = atomicAdd(&cursor[d], 1);
        es[rowstart[d] + p] = make_int2(e, src[e]);
    }
}

// fp32 -> fp16 stream convert (8 elems/thread)
__global__ void f2h_kernel(const float* __restrict__ in, __half* __restrict__ out, long n8) {
    long i = (long)blockIdx.x * blockDim.x + threadIdx.x;
    if (i < n8) {
        const float4* s = (const float4*)&in[i * 8];
        float4 a = s[0], b = s[1];
        __half2* d = (__half2*)&out[i * 8];
        d[0] = __float22half2_rn(make_float2(a.x, a.y));
        d[1] = __float22half2_rn(make_float2(a.z, a.w));
        d[2] = __float22half2_rn(make_float2(b.x, b.y));
        d[3] = __float22half2_rn(make_float2(b.z, b.w));
    }
}

// Repack [Wl|Wr] (fp32, row-major [K,Mh] each) into MFMA B-fragment order:
// Wfrag[((nt*KS+ks)*64+lane)*8+j] = Wcat[ks*32+(lane>>4)*8+j][nt*16+(lane&15)]
template <int K, int Mh>
__global__ void wprep_kernel(const float* __restrict__ Wl, const float* __restrict__ Wr,
                             __half* __restrict__ Wfrag) {
    constexpr int KS = K / 32;
    constexpr int BN = 2 * Mh;
    int i = blockIdx.x * blockDim.x + threadIdx.x;
    if (i >= K * BN) return;
    int j = i & 7;
    int lane = (i >> 3) & 63;
    int rest = i >> 9;
    int ks = rest % KS;
    int nt = rest / KS;
    int k = ks * 32 + ((lane >> 4) & 3) * 8 + j;
    int col = nt * 16 + (lane & 15);
    float v = (col < Mh) ? Wl[k * Mh + col] : Wr[k * Mh + (col - Mh)];
    Wfrag[i] = __float2half(v);
}

// MFMA dual GEMM: y = x[n,K] @ [Wl|Wr] + [bl|br], fp16 outputs split yl/yr.
// 4 waves; BM rows/block; BN=2*Mh cols; x converted fp32->fp16 during staging.
template <int K, int Mh, int BM>
__global__ __launch_bounds__(256) void gemm_mfma(
    const float* __restrict__ x, const __half* __restrict__ Wfrag,
    const float* __restrict__ bl, const float* __restrict__ br,
    __half* __restrict__ yl, __half* __restrict__ yr, int n) {
    constexpr int BN = 2 * Mh;
    constexpr int KS = K / 32;
    constexpr int NT = BN / 16;
    constexpr int RW = BM / 64;   // row-tiles per wave
    constexpr int LDP = K + 8;    // +16B pad: row stride 272/144B -> 2-way banks
    __shared__ __half xs[BM * LDP];
    int tid = threadIdx.x;
    int lane = tid & 63;
    int wave = tid >> 6;
    int node0 = blockIdx.x * BM;
    constexpr int ITER = (BM * K) / (256 * 4);
#pragma unroll
    for (int it = 0; it < ITER; ++it) {
        int base = (it * 256 + tid) * 4;
        int row = base / K, kk = base % K;
        float4 v = make_float4(0.f, 0.f, 0.f, 0.f);
        if (node0 + row < n) v = *(const float4*)&x[(size_t)(node0 + row) * K + kk];
        __half2* d = (__half2*)&xs[row * LDP + kk];
        d[0] = __float22half2_rn(make_float2(v.x, v.y));
        d[1] = __float22half2_rn(make_float2(v.z, v.w));
    }
    __syncthreads();
    f32x4 acc[RW][NT];
#pragma unroll
    for (int r = 0; r < RW; ++r)
#pragma unroll
        for (int t = 0; t < NT; ++t) {
            f32x4 z = {0.f, 0.f, 0.f, 0.f};
            acc[r][t] = z;
        }
    int r0 = lane & 15, kof = (lane >> 4) * 8;
#pragma unroll
    for (int ks = 0; ks < KS; ++ks) {
        half8 a[RW];
#pragma unroll
        for (int r = 0; r < RW; ++r) {
            int row = (wave * RW + r) * 16 + r0;
            a[r] = *reinterpret_cast<const half8*>(&xs[row * LDP + ks * 32 + kof]);
        }
#pragma unroll
        for (int t = 0; t < NT; ++t) {
            half8 b = *reinterpret_cast<const half8*>(&Wfrag[(((size_t)t * KS + ks) * 64 + lane) * 8]);
#pragma unroll
            for (int r = 0; r < RW; ++r)
                acc[r][t] = __builtin_amdgcn_mfma_f32_16x16x32_f16(a[r], b, acc[r][t], 0, 0, 0);
        }
    }
    // epilogue: C/D map col=lane&15, row=(lane>>4)*4+q  [m89-verified]
#pragma unroll
    for (int r = 0; r < RW; ++r) {
#pragma unroll
        for (int t = 0; t < NT; ++t) {
            int col = t * 16 + (lane & 15);
            float bv = (col < Mh) ? bl[col] : br[col - Mh];
#pragma unroll
            for (int q = 0; q < 4; ++q) {
                int node = node0 + (wave * RW + r) * 16 + (lane >> 4) * 4 + q;
                if (node < n) {
                    float v = acc[r][t][q] + bv;
                    if (col < Mh) yl[(size_t)node * Mh + col] = __float2half(v);
                    else          yr[(size_t)node * Mh + (col - Mh)] = __float2half(v);
                }
            }
        }
    }
}

// y[n,M] = x[n,K] @ W[K,M] + b ; fp32 (final head)
template <int K, int M, int NPB>
__global__ void linear_kernel(const float* __restrict__ x, const float* __restrict__ W,
                              const float* __restrict__ b, float* __restrict__ y, int n) {
    __shared__ float sx[NPB * K];
    int tid = threadIdx.x;
    int node0 = blockIdx.x * NPB;
    for (int i = tid; i < NPB * K; i += NPB * M) {
        int nn = node0 + i / K;
        sx[i] = (nn < n) ? x[(size_t)nn * K + (i % K)] : 0.f;
    }
    __syncthreads();
    int ln = tid / M, m = tid % M;
    int node = node0 + ln;
    if (node >= n) return;
    float acc = b[m];
#pragma unroll
    for (int k = 0; k < K; ++k) acc = fmaf(sx[ln * K + k], W[k * M + m], acc);
    y[(size_t)node * M + m] = acc;
}

// FUSED edge-logit + softmax + aggregate over dst-sorted edges.
// 2 ch/lane; xr once per node; 4-edge unrolled gather phase for MLP;
// ea@We via packed v_pk_fma_f16 chains.
template <int H, int C>
__global__ __launch_bounds__(256) void fused_edge_agg(
    const int* __restrict__ rowstart, const int2* __restrict__ es,
    const __half* __restrict__ eah,
    const float* __restrict__ We,    // [16, HC]
    const float* __restrict__ att,   // [HC]
    const __half* __restrict__ xl, const __half* __restrict__ xr,
    const float* __restrict__ bias, float* __restrict__ out, int n) {
    constexpr int HC = H * C;
    constexpr int LPN = HC / 2;
    constexpr int NPW = 64 / LPN;
    int gt = blockIdx.x * blockDim.x + threadIdx.x;
    int wave = gt >> 6;
    int lane = threadIdx.x & 63;
    int sub = lane / LPN;
    int j = lane % LPN;
    int ch0 = 2 * j;
    int node = wave * NPW + sub;
    if (node >= n) return;
    __half2 wh[16];
#pragma unroll
    for (int k = 0; k < 16; ++k) wh[k] = __float22half2_rn(*(const float2*)&We[k * HC + ch0]);
    float2 a2 = *(const float2*)&att[ch0];
    float2 xr2 = __half22float2(*(const __half2*)&xr[(size_t)node * HC + ch0]);
    int beg = rowstart[node], end = rowstart[node + 1];
    float denom = 0.f, acc0 = 0.f, acc1 = 0.f;

    auto gemv = [&](const float4& r0, const float4& r1, const __half2& xlh,
                    float& m0, float& m1, float2& xlf) {
        const __half2* h0 = (const __half2*)&r0;
        const __half2* h1 = (const __half2*)&r1;
        __half2 p0 = __hmul2(__low2half2(h0[0]), wh[0]);
        __half2 p1 = __hmul2(__high2half2(h0[0]), wh[1]);
        p0 = __hfma2(__low2half2(h0[1]), wh[2], p0);
        p1 = __hfma2(__high2half2(h0[1]), wh[3], p1);
        p0 = __hfma2(__low2half2(h0[2]), wh[4], p0);
        p1 = __hfma2(__high2half2(h0[2]), wh[5], p1);
        p0 = __hfma2(__low2half2(h0[3]), wh[6], p0);
        p1 = __hfma2(__high2half2(h0[3]), wh[7], p1);
        p0 = __hfma2(__low2half2(h1[0]), wh[8], p0);
        p1 = __hfma2(__high2half2(h1[0]), wh[9], p1);
        p0 = __hfma2(__low2half2(h1[1]), wh[10], p0);
        p1 = __hfma2(__high2half2(h1[1]), wh[11], p1);
        p0 = __hfma2(__low2half2(h1[2]), wh[12], p0);
        p1 = __hfma2(__high2half2(h1[2]), wh[13], p1);
        p0 = __hfma2(__low2half2(h1[3]), wh[14], p0);
        p1 = __hfma2(__high2half2(h1[3]), wh[15], p1);
        float2 mf = __half22float2(__hadd2(p0, p1));
        xlf = __half22float2(xlh);
        m0 = xlf.x + xr2.x + mf.x;
        m1 = xlf.y + xr2.y + mf.y;
    };
    auto logit = [&](float m0, float m1) -> float {
        m0 = (m0 > 0.f) ? m0 : 0.2f * m0;
        m1 = (m1 > 0.f) ? m1 : 0.2f * m1;
        float v = m0 * a2.x + m1 * a2.y;
#pragma unroll
        for (int msk = 1; msk < 16; msk <<= 1) v += __shfl_xor(v, msk, 64);
        return v;
    };

    int pp = beg;
    for (; pp + 4 <= end; pp += 4) {
        int2 er[4];
        float4 r0[4], r1[4];
        __half2 xh[4];
#pragma unroll
        for (int u = 0; u < 4; ++u) er[u] = es[pp + u];
#pragma unroll
        for (int u = 0; u < 4; ++u) {
            const float4* q = (const float4*)&eah[(size_t)er[u].x * 16];
            r0[u] = q[0];
            r1[u] = q[1];
            xh[u] = *(const __half2*)&xl[(size_t)er[u].y * HC + ch0];
        }
#pragma unroll
        for (int u = 0; u < 4; ++u) {
            float m0, m1;
            float2 xlf;
            gemv(r0[u], r1[u], xh[u], m0, m1, xlf);
            float w = __expf(logit(m0, m1));
            denom += w;
            acc0 = fmaf(xlf.x, w, acc0);
            acc1 = fmaf(xlf.y, w, acc1);
        }
    }
    for (; pp < end; ++pp) {
        int2 e2 = es[pp];
        const float4* q = (const float4*)&eah[(size_t)e2.x * 16];
        float4 r0 = q[0], r1 = q[1];
        __half2 xlh = *(const __half2*)&xl[(size_t)e2.y * HC + ch0];
        float m0, m1;
        float2 xlf;
        gemv(r0, r1, xlh, m0, m1, xlf);
        float w = __expf(logit(m0, m1));
        denom += w;
        acc0 = fmaf(xlf.x, w, acc0);
        acc1 = fmaf(xlf.y, w, acc1);
    }
    float2 b2 = *(const float2*)&bias[ch0];
    float inv = 1.f / (denom + 1e-16f);
    float o0 = acc0 * inv + b2.x;
    float o1 = acc1 * inv + b2.y;
    o0 = (o0 > 0.f) ? o0 : __expf(o0) - 1.f;
    o1 = (o1 > 0.f) ? o1 : __expf(o1) - 1.f;
    *(float2*)&out[(size_t)node * HC + ch0] = make_float2(o0, o1);
}

extern "C" void kernel_launch(void* const* d_in, const int* in_sizes, int n_in,
                              void* d_out, int out_size, void* d_ws, size_t ws_size,
                              hipStream_t stream) {
    const float* x     = (const float*)d_in[0];
    const int*   eidx  = (const int*)d_in[1];
    const float* eattr = (const float*)d_in[2];
    const float* W1l   = (const float*)d_in[3];
    const float* b1l   = (const float*)d_in[4];
    const float* W1r   = (const float*)d_in[5];
    const float* b1r   = (const float*)d_in[6];
    const float* W1e   = (const float*)d_in[7];
    const float* att1  = (const float*)d_in[8];
    const float* bias1 = (const float*)d_in[9];
    const float* W2l   = (const float*)d_in[10];
    const float* b2l   = (const float*)d_in[11];
    const float* W2r   = (const float*)d_in[12];
    const float* b2r   = (const float*)d_in[13];
    const float* W2e   = (const float*)d_in[14];
    const float* att2  = (const float*)d_in[15];
    const float* bias2 = (const float*)d_in[16];
    const float* Wlin  = (const float*)d_in[17];
    const float* blin  = (const float*)d_in[18];

    const int N = in_sizes[0] / 128;
    const int E = in_sizes[1] / 2;
    const int* src = eidx;
    const int* dst = eidx + E;

    char* p = (char*)d_ws;
    auto take = [&](size_t bytes) {
        char* r = p;
        p += (bytes + 255) & ~(size_t)255;
        return r;
    };
    int*    deg      = (int*)take((size_t)N * sizeof(int));
    int*    cursor   = (int*)take((size_t)N * sizeof(int));
    int*    rowstart = (int*)take((size_t)(N + 1) * sizeof(int));
    int*    bsum     = (int*)take(256 * sizeof(int));
    int2*   es       = (int2*)take((size_t)E * sizeof(int2));
    __half* A        = (__half*)take((size_t)N * 64 * sizeof(__half));  // xl (fp16)
    __half* B        = (__half*)take((size_t)N * 64 * sizeof(__half));  // xr (fp16)
    float*  Cbuf     = (float*)take((size_t)N * 64 * sizeof(float));    // h1 / h2 (fp32)
    __half* eah      = (__half*)take((size_t)E * 16 * sizeof(__half));  // eattr fp16
    __half* Wf1      = (__half*)take((size_t)128 * 128 * sizeof(__half));
    __half* Wf2      = (__half*)take((size_t)64 * 64 * sizeof(__half));

    // ---- CSR build + converts + weight repack ----
    (void)hipMemsetAsync(deg, 0, (size_t)N * sizeof(int), stream);
    (void)hipMemsetAsync(cursor, 0, (size_t)N * sizeof(int), stream);
    hist_kernel<<<(E + 255) / 256, 256, 0, stream>>>(dst, deg, E);
    {
        int nb = (N + 1023) / 1024;
        scan_part<<<nb, 256, 0, stream>>>(deg, bsum, N);
        scan_mid<<<1, 128, 0, stream>>>(bsum, rowstart, nb, N);
        scan_fin<<<nb, 256, 0, stream>>>(deg, bsum, rowstart, N);
    }
    scatter_kernel<<<(E + 255) / 256, 256, 0, stream>>>(src, dst, rowstart, cursor, es, E);
    {
        long n8 = (long)E * 16 / 8;
        f2h_kernel<<<(int)((n8 + 255) / 256), 256, 0, stream>>>(eattr, eah, n8);
    }
    wprep_kernel<128, 64><<<(128 * 128 + 255) / 256, 256, 0, stream>>>(W1l, W1r, Wf1);
    wprep_kernel<64, 32><<<(64 * 64 + 255) / 256, 256, 0, stream>>>(W2l, W2r, Wf2);

    // ---- Layer 1: H=2, C=32 ----
    gemm_mfma<128, 64, 64><<<(N + 63) / 64, 256, 0, stream>>>(x, Wf1, b1l, b1r, A, B, N);
    fused_edge_agg<2, 32><<<(int)(((size_t)((N + 1) / 2) * 64 + 255) / 256), 256, 0, stream>>>(
        rowstart, es, eah, W1e, att1, A, B, bias1, Cbuf, N);

    // ---- Layer 2: H=1, C=32 ----
    gemm_mfma<64, 32, 128><<<(N + 127) / 128, 256, 0, stream>>>(Cbuf, Wf2, b2l, b2r, A, B, N);
    fused_edge_agg<1, 32><<<(int)(((size_t)((N + 3) / 4) * 64 + 255) / 256), 256, 0, stream>>>(
        rowstart, es, eah, W2e, att2, A, B, bias2, Cbuf, N);

    // ---- Final linear ----
    linear_kernel<32, 32, 8><<<(N + 7) / 8, 256, 0, stream>>>(Cbuf, Wlin, blin, (float*)d_out, N);
}